// Round 3
// baseline (1512.155 us; speedup 1.0000x reference)
//
#include <hip/hip_runtime.h>

typedef unsigned int uint;
typedef unsigned short ushort;
typedef short short8 __attribute__((ext_vector_type(8)));
typedef float floatx4 __attribute__((ext_vector_type(4)));
typedef ushort ushortx8 __attribute__((ext_vector_type(8)));
typedef ushort ushortx4 __attribute__((ext_vector_type(4)));
typedef uint uintx4 __attribute__((ext_vector_type(4)));

#define DEV static __device__ __forceinline__

#define Bsz 16
#define Cch 512
#define Tt 128
#define Nn 64
#define Hh 8
#define HD 64
#define Pp 8192        /* T*N */
#define BPOS 131072    /* B*P  */
#define C3 1536

// chunk swizzle: tiles stored as 16-byte chunks (8 bf16); row has 8 chunks
DEV int swz(int row, int c8) { return row * 8 + (c8 ^ (row & 7) ^ ((row >> 3) & 7)); }

DEV ushort f2bf(float f) {
  uint u = __float_as_uint(f);
  return (ushort)((u + 0x7FFFu + ((u >> 16) & 1u)) >> 16);  // RNE
}
DEV float bf2f(ushort h) { return __uint_as_float(((uint)h) << 16); }

// ---------------------------------------------------------------------------
// elementwise fp32 -> bf16 (weights)
// ---------------------------------------------------------------------------
__global__ __launch_bounds__(256) void k_cvt(const float* __restrict__ src,
                                             ushort* __restrict__ dst, int n) {
  int gid = blockIdx.x * 256 + threadIdx.x;
  int i8 = gid * 8;
  if (i8 < n) {
    floatx4 a = *(const floatx4*)&src[i8];
    floatx4 b = *(const floatx4*)&src[i8 + 4];
    ushortx8 o;
#pragma unroll
    for (int j = 0; j < 4; ++j) { o[j] = f2bf(a[j]); o[j + 4] = f2bf(b[j]); }
    *(ushortx8*)&dst[i8] = o;
  }
}

// ---------------------------------------------------------------------------
// x fp32 [b][c][p] -> xT bf16 [b][p][c]  (64x64 tiles via swizzled LDS)
// ---------------------------------------------------------------------------
__global__ __launch_bounds__(256) void k_transpose_x(const float* __restrict__ x,
                                                     ushort* __restrict__ xT) {
  int p0 = blockIdx.x * 64, c0 = blockIdx.y * 64, b = blockIdx.z;
  __shared__ __align__(16) ushort sm[4096];
  int tid = threadIdx.x;
  const float* xb = x + (size_t)b * Cch * Pp;
  ushort* xTb = xT + (size_t)b * Pp * Cch;
#pragma unroll
  for (int it = 0; it < 4; ++it) {
    int cc = tid + it * 256;
    int r = cc >> 4, c4 = cc & 15;
    floatx4 v = *(const floatx4*)&xb[(size_t)(c0 + r) * Pp + p0 + c4 * 4];
    ushortx4 o;
#pragma unroll
    for (int j = 0; j < 4; ++j) o[j] = f2bf(v[j]);
    *(ushortx4*)&sm[swz(r, c4 >> 1) * 8 + (c4 & 1) * 4] = o;
  }
  __syncthreads();
#pragma unroll
  for (int it = 0; it < 2; ++it) {
    int cc = tid + it * 256;
    int pl = cc >> 3, c8 = cc & 7;
    ushortx8 o;
#pragma unroll
    for (int j = 0; j < 8; ++j) {
      int c = c8 * 8 + j;
      o[j] = sm[swz(c, pl >> 3) * 8 + (pl & 7)];
    }
    *(ushortx8*)&xTb[(size_t)(p0 + pl) * Cch + c0 + c8 * 8] = o;
  }
}

// ---------------------------------------------------------------------------
// D_bf16[m][n] = sum_k A[m][k]*W[n][k] + bias[n]  (A,W bf16; bias fp32)
// 128x128 block tile, BK=64, 4 waves each 64x64
// ---------------------------------------------------------------------------
__global__ __launch_bounds__(256) void k_gemm_bt(const ushort* __restrict__ A,
                                                 const ushort* __restrict__ W,
                                                 const float* __restrict__ bias,
                                                 ushort* __restrict__ D,
                                                 int K, int ldD) {
  __shared__ __align__(16) ushort sm[16384];
  ushort* sA = sm;
  ushort* sB = sm + 8192;
  int tid = threadIdx.x;
  int lane = tid & 63, w = tid >> 6;
  int wm = (w & 1) * 64, wn = (w >> 1) * 64;
  size_t m0 = (size_t)blockIdx.y * 128;
  size_t n0 = (size_t)blockIdx.x * 128;

  floatx4 zero4 = {0.f, 0.f, 0.f, 0.f};
  floatx4 acc[4][4];
#pragma unroll
  for (int i = 0; i < 4; ++i)
#pragma unroll
    for (int j = 0; j < 4; ++j) acc[i][j] = zero4;

  for (int kb = 0; kb < K; kb += 64) {
    uintx4 ra[4], rb[4];
#pragma unroll
    for (int it = 0; it < 4; ++it) {
      int cc = tid + it * 256;
      int r = cc >> 3, c8 = cc & 7;
      ra[it] = *(const uintx4*)&A[(m0 + r) * K + kb + c8 * 8];
      rb[it] = *(const uintx4*)&W[(n0 + r) * K + kb + c8 * 8];
    }
    __syncthreads();
#pragma unroll
    for (int it = 0; it < 4; ++it) {
      int cc = tid + it * 256;
      int r = cc >> 3, c8 = cc & 7;
      *(uintx4*)&sA[swz(r, c8) * 8] = ra[it];
      *(uintx4*)&sB[swz(r, c8) * 8] = rb[it];
    }
    __syncthreads();
#pragma unroll
    for (int kk = 0; kk < 2; ++kk) {
      int g = kk * 4 + (lane >> 4);
      int rr = lane & 15;
      short8 af[4], bf[4];
#pragma unroll
      for (int i = 0; i < 4; ++i) af[i] = *(const short8*)&sA[swz(wm + i * 16 + rr, g) * 8];
#pragma unroll
      for (int j = 0; j < 4; ++j) bf[j] = *(const short8*)&sB[swz(wn + j * 16 + rr, g) * 8];
#pragma unroll
      for (int i = 0; i < 4; ++i)
#pragma unroll
        for (int j = 0; j < 4; ++j)
          acc[i][j] = __builtin_amdgcn_mfma_f32_16x16x32_bf16(af[i], bf[j], acc[i][j], 0, 0, 0);
    }
  }

  __syncthreads();
  int quad = lane >> 4, col = lane & 15;
#pragma unroll
  for (int j = 0; j < 4; ++j) {
    int n_loc = wn + j * 16 + col;
    float bj = bias[n0 + n_loc];
#pragma unroll
    for (int i = 0; i < 4; ++i)
#pragma unroll
      for (int r = 0; r < 4; ++r) {
        int m_loc = wm + i * 16 + quad * 4 + r;
        sm[(m_loc * 16 + ((n_loc >> 3) ^ (m_loc & 7) ^ ((m_loc >> 3) & 7))) * 8 + (n_loc & 7)] =
            f2bf(acc[i][j][r] + bj);
      }
  }
  __syncthreads();
#pragma unroll
  for (int it = 0; it < 8; ++it) {
    int cc = tid + it * 256;
    int m_loc = cc >> 4, cn = cc & 15;
    uintx4 v = *(const uintx4*)&sm[(m_loc * 16 + (cn ^ (m_loc & 7) ^ ((m_loc >> 3) & 7))) * 8];
    *(uintx4*)&D[(m0 + m_loc) * (size_t)ldD + n0 + cn * 8] = v;
  }
}

// ---------------------------------------------------------------------------
// GEMM2: D_fp32[n][m] = sum_k A[m][k]*W[n][k] + bias[n]   (transposed fp32 out)
// A: aT_b bf16 [8192x512], W: w_proj bf16 [512x512], D: y_b fp32 [512][ldD=8192]
// epilogue: two half-tiles (64 n-rows x 128 m) through 32KB LDS, coalesced
// ---------------------------------------------------------------------------
__global__ __launch_bounds__(256) void k_gemm2_t(const ushort* __restrict__ A,
                                                 const ushort* __restrict__ W,
                                                 const float* __restrict__ bias,
                                                 float* __restrict__ D,
                                                 int K, int ldD) {
  __shared__ __align__(16) ushort sm[16384];
  ushort* sA = sm;
  ushort* sB = sm + 8192;
  float* smf = (float*)sm;
  int tid = threadIdx.x;
  int lane = tid & 63, w = tid >> 6;
  int wm = (w & 1) * 64, wn = (w >> 1) * 64;
  size_t m0 = (size_t)blockIdx.y * 128;
  size_t n0 = (size_t)blockIdx.x * 128;

  floatx4 zero4 = {0.f, 0.f, 0.f, 0.f};
  floatx4 acc[4][4];
#pragma unroll
  for (int i = 0; i < 4; ++i)
#pragma unroll
    for (int j = 0; j < 4; ++j) acc[i][j] = zero4;

  for (int kb = 0; kb < K; kb += 64) {
    uintx4 ra[4], rb[4];
#pragma unroll
    for (int it = 0; it < 4; ++it) {
      int cc = tid + it * 256;
      int r = cc >> 3, c8 = cc & 7;
      ra[it] = *(const uintx4*)&A[(m0 + r) * K + kb + c8 * 8];
      rb[it] = *(const uintx4*)&W[(n0 + r) * K + kb + c8 * 8];
    }
    __syncthreads();
#pragma unroll
    for (int it = 0; it < 4; ++it) {
      int cc = tid + it * 256;
      int r = cc >> 3, c8 = cc & 7;
      *(uintx4*)&sA[swz(r, c8) * 8] = ra[it];
      *(uintx4*)&sB[swz(r, c8) * 8] = rb[it];
    }
    __syncthreads();
#pragma unroll
    for (int kk = 0; kk < 2; ++kk) {
      int g = kk * 4 + (lane >> 4);
      int rr = lane & 15;
      short8 af[4], bf[4];
#pragma unroll
      for (int i = 0; i < 4; ++i) af[i] = *(const short8*)&sA[swz(wm + i * 16 + rr, g) * 8];
#pragma unroll
      for (int j = 0; j < 4; ++j) bf[j] = *(const short8*)&sB[swz(wn + j * 16 + rr, g) * 8];
#pragma unroll
      for (int i = 0; i < 4; ++i)
#pragma unroll
        for (int j = 0; j < 4; ++j)
          acc[i][j] = __builtin_amdgcn_mfma_f32_16x16x32_bf16(af[i], bf[j], acc[i][j], 0, 0, 0);
    }
  }

  int quad = lane >> 4, col = lane & 15;
#pragma unroll
  for (int h = 0; h < 2; ++h) {
    __syncthreads();
    if ((w >> 1) == h) {  // waves whose wn == h*64 own this half
#pragma unroll
      for (int j = 0; j < 4; ++j) {
        int n1 = j * 16 + col;  // row within half
        float bj = bias[n0 + h * 64 + n1];
#pragma unroll
        for (int i = 0; i < 4; ++i) {
          int mb = wm + i * 16 + quad * 4;
          floatx4 v4;
#pragma unroll
          for (int r = 0; r < 4; ++r) v4[r] = acc[i][j][r] + bj;
          *(floatx4*)&smf[n1 * 128 + (mb ^ ((n1 & 7) << 2))] = v4;
        }
      }
    }
    __syncthreads();
#pragma unroll
    for (int it = 0; it < 8; ++it) {
      int cc = tid + it * 256;
      int n2 = cc >> 5, ck = cc & 31;
      floatx4 v = *(const floatx4*)&smf[n2 * 128 + ((ck * 4) ^ ((n2 & 7) << 2))];
      *(floatx4*)&D[(n0 + h * 64 + n2) * (size_t)ldD + m0 + ck * 4] = v;
    }
  }
}

// ---------------------------------------------------------------------------
// attention for ONE batch: block per (h,t); S = q k^T * 0.125 ; O = S v
// qkv_b bf16 [p][1536]; aT_b bf16 [p][512]
// ---------------------------------------------------------------------------
__global__ __launch_bounds__(256) void k_attn(const ushort* __restrict__ qkv_b,
                                              ushort* __restrict__ aT_b) {
  int bx = blockIdx.x;
  int t = bx & 127, h = bx >> 7;
  __shared__ __align__(16) ushort sm[16384];
  ushort* qs = sm;
  ushort* ks = sm + 4096;
  ushort* vt = sm + 8192;
  ushort* ss = sm + 12288;
  int tid = threadIdx.x, lane = tid & 63, w = tid >> 6;
  int quad = lane >> 4, col = lane & 15;
  const ushort* base = qkv_b + (size_t)(t * 64) * C3 + h * 64;

#pragma unroll
  for (int it = 0; it < 2; ++it) {
    int cc = tid + it * 256;
    int n = cc >> 3, d8 = cc & 7;
    uintx4 vq = *(const uintx4*)&base[(size_t)n * C3 + d8 * 8];
    uintx4 vk = *(const uintx4*)&base[(size_t)n * C3 + 512 + d8 * 8];
    *(uintx4*)&qs[swz(n, d8) * 8] = vq;
    *(uintx4*)&ks[swz(n, d8) * 8] = vk;
    ushortx8 vv = *(const ushortx8*)&base[(size_t)n * C3 + 1024 + d8 * 8];
#pragma unroll
    for (int j = 0; j < 8; ++j) {
      int dp = d8 * 8 + j;
      vt[swz(dp, n >> 3) * 8 + (n & 7)] = vv[j];  // vT[d][m]
    }
  }
  __syncthreads();

  floatx4 zero4 = {0.f, 0.f, 0.f, 0.f};
  floatx4 accs[4] = {zero4, zero4, zero4, zero4};
#pragma unroll
  for (int kk = 0; kk < 2; ++kk) {
    int g = kk * 4 + quad;
    short8 aq = *(const short8*)&qs[swz(w * 16 + col, g) * 8];
#pragma unroll
    for (int j = 0; j < 4; ++j) {
      short8 bk = *(const short8*)&ks[swz(j * 16 + col, g) * 8];
      accs[j] = __builtin_amdgcn_mfma_f32_16x16x32_bf16(aq, bk, accs[j], 0, 0, 0);
    }
  }
#pragma unroll
  for (int j = 0; j < 4; ++j)
#pragma unroll
    for (int r = 0; r < 4; ++r) {
      int n = w * 16 + quad * 4 + r, m = j * 16 + col;
      ss[swz(n, m >> 3) * 8 + (m & 7)] = f2bf(accs[j][r] * 0.125f);
    }
  __syncthreads();

  floatx4 acco[4] = {zero4, zero4, zero4, zero4};
#pragma unroll
  for (int kk = 0; kk < 2; ++kk) {
    int g = kk * 4 + quad;
    short8 as = *(const short8*)&ss[swz(w * 16 + col, g) * 8];
#pragma unroll
    for (int j = 0; j < 4; ++j) {
      short8 bv = *(const short8*)&vt[swz(j * 16 + col, g) * 8];
      acco[j] = __builtin_amdgcn_mfma_f32_16x16x32_bf16(as, bv, acco[j], 0, 0, 0);
    }
  }
#pragma unroll
  for (int j = 0; j < 4; ++j)
#pragma unroll
    for (int r = 0; r < 4; ++r) {
      int n = w * 16 + quad * 4 + r, dp = j * 16 + col;
      qs[swz(n, dp >> 3) * 8 + (dp & 7)] = f2bf(acco[j][r]);  // qs dead, reuse
    }
  __syncthreads();
  ushort* aTb = aT_b + (size_t)(t * 64) * Cch + h * 64;
#pragma unroll
  for (int it = 0; it < 2; ++it) {
    int cc = tid + it * 256;
    int n = cc >> 3, c8 = cc & 7;
    uintx4 v = *(const uintx4*)&qs[swz(n, c8) * 8];
    *(uintx4*)&aTb[(size_t)n * Cch + c8 * 8] = v;
  }
}

// ---------------------------------------------------------------------------
// BN statistics (fp32 channel-major y) + finalize + in-place BN+residual
// ---------------------------------------------------------------------------
__global__ __launch_bounds__(256) void k_zero(float* p, int n) {
  int i = blockIdx.x * 256 + threadIdx.x;
  if (i < n) p[i] = 0.f;
}

__global__ __launch_bounds__(256) void k_stats_cm(const float* __restrict__ y,
                                                  float* __restrict__ sums,
                                                  float* __restrict__ sqs) {
  int c = blockIdx.x, b = blockIdx.y;
  const float* row = y + ((size_t)b * Cch + c) * Pp;
  int tid = threadIdx.x;
  float s = 0.f, q = 0.f;
#pragma unroll
  for (int it = 0; it < 8; ++it) {
    floatx4 v = *(const floatx4*)&row[it * 1024 + tid * 4];
#pragma unroll
    for (int j = 0; j < 4; ++j) {
      s += v[j];
      q += v[j] * v[j];
    }
  }
#pragma unroll
  for (int off = 32; off > 0; off >>= 1) {
    s += __shfl_down(s, off);
    q += __shfl_down(q, off);
  }
  __shared__ float redS[4], redQ[4];
  if ((tid & 63) == 0) {
    redS[tid >> 6] = s;
    redQ[tid >> 6] = q;
  }
  __syncthreads();
  if (tid == 0) {
    atomicAdd(&sums[c], redS[0] + redS[1] + redS[2] + redS[3]);
    atomicAdd(&sqs[c], redQ[0] + redQ[1] + redQ[2] + redQ[3]);
  }
}

__global__ __launch_bounds__(256) void k_bnfin(const float* __restrict__ sums,
                                               const float* __restrict__ sqs,
                                               const float* __restrict__ gamma,
                                               const float* __restrict__ beta,
                                               float* __restrict__ scaleS,
                                               float* __restrict__ shiftS) {
  int c = threadIdx.x + blockIdx.x * 256;
  if (c < Cch) {
    float inv = 1.0f / (float)BPOS;
    float mean = sums[c] * inv;
    float var = sqs[c] * inv - mean * mean;
    float sc = gamma[c] * rsqrtf(var + 1e-5f);
    scaleS[c] = sc;
    shiftS[c] = beta[c] - mean * sc;
  }
}

// y (= d_out fp32, channel-major) in place: y = y*scale[c] + shift[c] + x
__global__ __launch_bounds__(256) void k_final(const float* __restrict__ x,
                                               float* __restrict__ y,
                                               const float* __restrict__ scaleS,
                                               const float* __restrict__ shiftS) {
  size_t gid = (size_t)blockIdx.x * 256 + threadIdx.x;
  size_t i4 = gid * 4;
  int c = (int)((i4 >> 13) & 511);
  float sc = scaleS[c], sh = shiftS[c];
  floatx4 yv = *(floatx4*)&y[i4];
  floatx4 xv = *(const floatx4*)&x[i4];
  floatx4 o;
#pragma unroll
  for (int j = 0; j < 4; ++j) o[j] = yv[j] * sc + sh + xv[j];
  *(floatx4*)&y[i4] = o;
}

// ---------------------------------------------------------------------------
extern "C" void kernel_launch(void* const* d_in, const int* in_sizes, int n_in,
                              void* d_out, int out_size, void* d_ws, size_t ws_size,
                              hipStream_t stream) {
  const float* x      = (const float*)d_in[0];
  const float* w_qkv  = (const float*)d_in[1];
  const float* b_qkv  = (const float*)d_in[2];
  const float* w_proj = (const float*)d_in[3];
  const float* b_proj = (const float*)d_in[4];
  const float* gamma  = (const float*)d_in[5];
  const float* beta   = (const float*)d_in[6];
  float* outf = (float*)d_out;  // 67,108,864 fp32 = 268,435,456 B

  // ws (~36 MB): qkv_b | aT_b | wqkvb | wprojb | stats
  char* ws = (char*)d_ws;
  ushort* qkv_b  = (ushort*)ws;                         // 25,165,824 B
  ushort* aT_b   = (ushort*)(ws + 25165824ull);         //  8,388,608 B
  ushort* wqkvb  = (ushort*)(ws + 33554432ull);         //  1,572,864 B
  ushort* wprojb = (ushort*)(ws + 35127296ull);         //    524,288 B
  float*  st     = (float*)(ws + 35651584ull);          //      8 KB
  float* sums = st, *sqs = st + 512, *scaleS = st + 1024, *shiftS = st + 1536;

  // d_out doubles as scratch: xT bf16 [16][8192][512] in the UPPER half
  // (bytes 134,217,728..268,435,456). GEMM2 writes fp32 y into out slab b
  // (16,777,216 B each); slab b (b>=8) overwrites xT batches 2b-16, 2b-15,
  // which are dead by then (GEMM1 runs in batch order).
  ushort* xT = (ushort*)((char*)d_out + 134217728ull);

  k_zero<<<dim3(8), 256, 0, stream>>>(st, 2048);
  k_cvt<<<dim3(384), 256, 0, stream>>>(w_qkv, wqkvb, 3 * Cch * Cch);
  k_cvt<<<dim3(128), 256, 0, stream>>>(w_proj, wprojb, Cch * Cch);
  k_transpose_x<<<dim3(Pp / 64, Cch / 64, Bsz), 256, 0, stream>>>(x, xT);

  for (int b = 0; b < Bsz; ++b) {
    const ushort* xT_b = xT + (size_t)b * Pp * Cch;
    float* y_b = outf + (size_t)b * Cch * Pp;  // fp32 channel-major slab
    k_gemm_bt<<<dim3(C3 / 128, Pp / 128), 256, 0, stream>>>(
        xT_b, wqkvb, b_qkv, qkv_b, Cch, C3);
    k_attn<<<dim3(Hh * Tt), 256, 0, stream>>>(qkv_b, aT_b);
    k_gemm2_t<<<dim3(Cch / 128, Pp / 128), 256, 0, stream>>>(
        aT_b, wprojb, b_proj, y_b, Cch, Pp);
  }

  k_stats_cm<<<dim3(Cch, Bsz), 256, 0, stream>>>(outf, sums, sqs);
  k_bnfin<<<dim3(2), 256, 0, stream>>>(sums, sqs, gamma, beta, scaleS, shiftS);
  k_final<<<dim3(BPOS * Cch / 4 / 256), 256, 0, stream>>>(x, outf, scaleS, shiftS);
}